// Round 5
// baseline (465.170 us; speedup 1.0000x reference)
//
#include <hip/hip_runtime.h>

// Problem constants (from reference)
constexpr int B_     = 4;
constexpr int N_UP   = 16384;
constexpr int N_DOWN = 4096;
constexpr int C_UP_  = 384;
constexpr int C_DOWN_= 512;
constexpr int C_OUT_ = 512;

// KNN chunking
constexpr int S_CHUNKS = 16;               // candidate chunks
constexpr int CH       = N_DOWN / S_CHUNKS; // 256 candidates per chunk

typedef __attribute__((ext_vector_type(8))) short bf16x8;
typedef __attribute__((ext_vector_type(4))) float f32x4;
typedef __attribute__((ext_vector_type(4))) float f4v;

// f32 -> bf16 round-to-nearest-even (bit-exact, no API dependence)
__device__ inline unsigned short f2bf(float f) {
    unsigned int u = __float_as_uint(f);
    return (unsigned short)((u + 0x7FFFu + ((u >> 16) & 1u)) >> 16);
}

// async global->LDS, 16B per lane. HW: dest = wave-uniform base + lane*16,
// so lds must be computed as base + lane*16 in lane order (it is, below).
__device__ inline void load_lds_128(const void* g, void* l) {
    __builtin_amdgcn_global_load_lds(
        (const __attribute__((address_space(1))) unsigned int*)g,
        (__attribute__((address_space(3))) unsigned int*)l, 16, 0, 0);
}

// ---------------------------------------------------------------------------
// pts4[b][m] = {x, y, z, (x*x+y*y)+z*z}   (ref rounding order, no contract)
// ---------------------------------------------------------------------------
__global__ void prep_pts4(const float* __restrict__ down_pts, float4* __restrict__ pts4) {
#pragma clang fp contract(off)
    const int i = blockIdx.x * 256 + threadIdx.x;   // 0 .. B*N_DOWN-1
    const float x = down_pts[i * 3 + 0];
    const float y = down_pts[i * 3 + 1];
    const float z = down_pts[i * 3 + 2];
    float4 p; p.x = x; p.y = y; p.z = z; p.w = (x * x + y * y) + z * z;
    pts4[i] = p;
}

// ---------------------------------------------------------------------------
// Per-chunk exact top-3. Grid (N_UP/512, B, S_CHUNKS); 2 queries per thread.
//
// Candidates are WAVE-UNIFORM -> address-space(4) + uniform index = s_load
// into SGPRs (R3-verified: no LDS, no VALU addr math). QPT=2 amortizes all
// per-iteration overhead over two pairs; explicit 4-candidate (64B) scalar
// prefetch double-buffer hides s_load latency behind ~576 cycles of compute.
//
// dist = fmaf(-2, cross, u2 + d2) -- bit-identical to ref's
// (u2+d2) - 2*cross (2*cross exact, single rounding).
// Distance tuple: branchless min/med3 (stable-insert-exact, incl. ties).
// Index tuple: straight-line 5 cndmask (no divergent branch).
// ---------------------------------------------------------------------------
__launch_bounds__(256, 8)
__global__ void knn_chunk(const float* __restrict__ up_pts,   // [B,N_UP,3]
                          const float4* __restrict__ pts4,    // [B,N_DOWN]
                          float* __restrict__ part_d,         // [B*N_UP, S*3]
                          int*   __restrict__ part_i)
{
#pragma clang fp contract(off)
    const int b = blockIdx.y;
    const int s = blockIdx.z;
    const int mbase = s * CH;

    typedef __attribute__((address_space(4))) const f4v cst_f4;
    const cst_f4* sp = (const cst_f4*)(pts4 + (size_t)b * N_DOWN + mbase);

    const int n0 = blockIdx.x * 512;
    const int g0 = b * N_UP + n0 + threadIdx.x;
    const int g1 = g0 + 256;

    const float ax = up_pts[(size_t)g0 * 3 + 0];
    const float ay = up_pts[(size_t)g0 * 3 + 1];
    const float az = up_pts[(size_t)g0 * 3 + 2];
    const float au = (ax * ax + ay * ay) + az * az;
    const float bx = up_pts[(size_t)g1 * 3 + 0];
    const float by = up_pts[(size_t)g1 * 3 + 1];
    const float bz = up_pts[(size_t)g1 * 3 + 2];
    const float bu = (bx * bx + by * by) + bz * bz;

    float a0 = 1e30f, a1 = 1e30f, a2 = 1e30f;  int ia0 = 0, ia1 = 0, ia2 = 0;
    float b0 = 1e30f, b1 = 1e30f, b2 = 1e30f;  int ib0 = 0, ib1 = 0, ib2 = 0;

    // prefetch double-buffer: group of 4 candidates = 64B scalar load
    f4v c0 = sp[0], c1 = sp[1], c2 = sp[2], c3 = sp[3];

#define PAIR(P, GI)                                                        \
    {                                                                      \
        const float cra = (ax * (P).x + ay * (P).y) + az * (P).z;          \
        const float da  = __builtin_fmaf(-2.0f, cra, au + (P).w);          \
        const bool ca2 = da < a2, ca1 = da < a1, ca0 = da < a0;            \
        { const int t = ca2 ? (GI) : ia2; ia2 = ca1 ? ia1 : t; }           \
        { const int t = ca1 ? (GI) : ia1; ia1 = ca0 ? ia0 : t; }           \
        ia0 = ca0 ? (GI) : ia0;                                            \
        const float na1 = __builtin_amdgcn_fmed3f(da, a0, a1);             \
        const float na2 = __builtin_amdgcn_fmed3f(da, a1, a2);             \
        a0 = fminf(a0, da); a1 = na1; a2 = na2;                            \
        const float crb = (bx * (P).x + by * (P).y) + bz * (P).z;          \
        const float db  = __builtin_fmaf(-2.0f, crb, bu + (P).w);          \
        const bool cb2 = db < b2, cb1 = db < b1, cb0 = db < b0;            \
        { const int t = cb2 ? (GI) : ib2; ib2 = cb1 ? ib1 : t; }           \
        { const int t = cb1 ? (GI) : ib1; ib1 = cb0 ? ib0 : t; }           \
        ib0 = cb0 ? (GI) : ib0;                                            \
        const float nb1 = __builtin_amdgcn_fmed3f(db, b0, b1);             \
        const float nb2 = __builtin_amdgcn_fmed3f(db, b1, b2);             \
        b0 = fminf(b0, db); b1 = nb1; b2 = nb2;                            \
    }

#pragma unroll 1
    for (int mg = 0; mg < CH; mg += 4) {
        // issue next group's s_loads before computing current (wrap keeps
        // the address in-bounds; last group's prefetch values are unused)
        const int nx = (mg + 4 < CH) ? (mg + 4) : 0;
        const f4v p0 = sp[nx], p1 = sp[nx + 1], p2 = sp[nx + 2], p3 = sp[nx + 3];
        PAIR(c0, mbase + mg + 0);
        PAIR(c1, mbase + mg + 1);
        PAIR(c2, mbase + mg + 2);
        PAIR(c3, mbase + mg + 3);
        c0 = p0; c1 = p1; c2 = p2; c3 = p3;
    }
#undef PAIR

    float* pd = part_d + (size_t)g0 * (S_CHUNKS * 3) + s * 3;
    int*   pi = part_i + (size_t)g0 * (S_CHUNKS * 3) + s * 3;
    pd[0] = a0; pd[1] = a1; pd[2] = a2;
    pi[0] = ia0; pi[1] = ia1; pi[2] = ia2;
    pd = part_d + (size_t)g1 * (S_CHUNKS * 3) + s * 3;
    pi = part_i + (size_t)g1 * (S_CHUNKS * 3) + s * 3;
    pd[0] = b0; pd[1] = b1; pd[2] = b2;
    pi[0] = ib0; pi[1] = ib1; pi[2] = ib2;
}

// ---------------------------------------------------------------------------
// Merge S*3 exact candidates (ascending chunk = ascending index => identical
// tie-breaks to the full scan), compute normalized inverse-distance weights.
// ---------------------------------------------------------------------------
__launch_bounds__(256)
__global__ void knn_merge(const float* __restrict__ part_d,
                          const int*   __restrict__ part_i,
                          int*  __restrict__ idx_out,   // [B*N_UP,3]
                          float* __restrict__ w_out)    // [B*N_UP,3]
{
    const int g = blockIdx.x * 256 + threadIdx.x;
    const float4* pd = (const float4*)(part_d + (size_t)g * (S_CHUNKS * 3));
    const int4*   pi = (const int4*)(part_i + (size_t)g * (S_CHUNKS * 3));

    float d0 = 1e30f, d1 = 1e30f, d2 = 1e30f;
    int   i0 = 0,     i1 = 0,     i2 = 0;

#pragma unroll
    for (int q = 0; q < (S_CHUNKS * 3) / 4; ++q) {
        const float4 dv = pd[q];
        const int4   iv = pi[q];
        const float dd[4] = {dv.x, dv.y, dv.z, dv.w};
        const int   ii[4] = {iv.x, iv.y, iv.z, iv.w};
#pragma unroll
        for (int j = 0; j < 4; ++j) {
            const float d = dd[j];
            const int   m = ii[j];
            const bool c2 = d < d2;
            const bool c1 = d < d1;
            const bool c0 = d < d0;
            { const int t = c2 ? m : i2; i2 = c1 ? i1 : t; }
            { const int t = c1 ? m : i1; i1 = c0 ? i0 : t; }
            i0 = c0 ? m : i0;
            const float nd1 = __builtin_amdgcn_fmed3f(d, d0, d1);
            const float nd2 = __builtin_amdgcn_fmed3f(d, d1, d2);
            d0 = fminf(d0, d);
            d1 = nd1;
            d2 = nd2;
        }
    }

    const float w0 = 1.0f / (d0 + 1e-8f);
    const float w1 = 1.0f / (d1 + 1e-8f);
    const float w2 = 1.0f / (d2 + 1e-8f);
    const float s  = (w0 + w1) + w2;
    idx_out[(size_t)g * 3 + 0] = i0;
    idx_out[(size_t)g * 3 + 1] = i1;
    idx_out[(size_t)g * 3 + 2] = i2;
    w_out[(size_t)g * 3 + 0] = w0 / s;
    w_out[(size_t)g * 3 + 1] = w1 / s;
    w_out[(size_t)g * 3 + 2] = w2 / s;
}

// ---------------------------------------------------------------------------
// f32 -> bf16 conversion, 4 elements/thread
// ---------------------------------------------------------------------------
__launch_bounds__(256)
__global__ void cvt_bf16(const float* __restrict__ src, unsigned short* __restrict__ dst) {
    const size_t i = (size_t)blockIdx.x * 256 + threadIdx.x;
    const float4 v = ((const float4*)src)[i];
    ushort4 o;
    o.x = f2bf(v.x); o.y = f2bf(v.y); o.z = f2bf(v.z); o.w = f2bf(v.w);
    ((ushort4*)dst)[i] = o;
}

// ---------------------------------------------------------------------------
// bf16 MFMA GEMM: C[m,n] = sum_k A[m,k]*W[n,k] (+bias) (+interp gather)
// 128x128 tile, BK=32, 256 threads = 4 waves (2x2 of 64x64), 16x16x32 MFMA.
// m97-style global_load_lds width-16 staging.
// ---------------------------------------------------------------------------
template<bool INTERP>
__launch_bounds__(256)
__global__ void gemm_bf16(const unsigned short* __restrict__ A,  // [M,K] bf16
                          const unsigned short* __restrict__ W,  // [N,K] bf16
                          const float* __restrict__ bias,        // [N]
                          float* __restrict__ C,                 // [M,N] f32
                          const int K, const int N,
                          const int* __restrict__ knn_idx,       // [M,3]
                          const float* __restrict__ knn_w,       // [M,3]
                          const float* __restrict__ down_f)      // [B*N_DOWN,N]
{
    __shared__ __align__(16) unsigned short As[128 * 32];
    __shared__ __align__(16) unsigned short Bs[128 * 32];
    __shared__ int   sI[128 * 3];
    __shared__ float sV[128 * 3];

    const int tid  = threadIdx.x;
    const int lane = tid & 63;
    const int wv   = tid >> 6;
    const int wrow = (wv >> 1) * 64;
    const int wcol = (wv & 1) * 64;
    const int quad = lane >> 4;
    const int l16  = lane & 15;
    const int m0   = blockIdx.y * 128;
    const int n0   = blockIdx.x * 128;

    if (INTERP) {
        for (int t = tid; t < 384; t += 256) {
            sI[t] = knn_idx[(size_t)m0 * 3 + t];
            sV[t] = knn_w[(size_t)m0 * 3 + t];
        }
    }

    f32x4 acc[4][4];
#pragma unroll
    for (int i = 0; i < 4; ++i)
#pragma unroll
        for (int j = 0; j < 4; ++j) {
            acc[i][j][0] = 0.f; acc[i][j][1] = 0.f;
            acc[i][j][2] = 0.f; acc[i][j][3] = 0.f;
        }

    // staging geometry: LDS tile is [row][32k] bf16 (64 B rows); each wave
    // covers 2 KiB as two 1 KiB chunks of lane*16.
    const int o0 = wv * 2048 + lane * 16;
    const int o1 = o0 + 1024;
    const int r0 = o0 >> 6, kk0 = o0 & 63;
    const int r1 = o1 >> 6, kk1 = o1 & 63;
    const char* Ab = (const char*)A;
    const char* Wb = (const char*)W;
    const size_t Ks = (size_t)K;

    for (int k0 = 0; k0 < K; k0 += 32) {
        __syncthreads();   // previous iter's ds_reads done before overwrite
        load_lds_128(Ab + ((size_t)(m0 + r0) * Ks + k0) * 2 + kk0, (char*)As + o0);
        load_lds_128(Ab + ((size_t)(m0 + r1) * Ks + k0) * 2 + kk1, (char*)As + o1);
        load_lds_128(Wb + ((size_t)(n0 + r0) * Ks + k0) * 2 + kk0, (char*)Bs + o0);
        load_lds_128(Wb + ((size_t)(n0 + r1) * Ks + k0) * 2 + kk1, (char*)Bs + o1);
        __syncthreads();   // vmcnt(0) drained by compiler before barrier

        bf16x8 af[4], bw[4];
#pragma unroll
        for (int i = 0; i < 4; ++i)
            af[i] = *(const bf16x8*)(As + (wrow + i * 16 + l16) * 32 + quad * 8);
#pragma unroll
        for (int j = 0; j < 4; ++j)
            bw[j] = *(const bf16x8*)(Bs + (wcol + j * 16 + l16) * 32 + quad * 8);
#pragma unroll
        for (int i = 0; i < 4; ++i)
#pragma unroll
            for (int j = 0; j < 4; ++j)
                acc[i][j] = __builtin_amdgcn_mfma_f32_16x16x32_bf16(
                    af[i], bw[j], acc[i][j], 0, 0, 0);
    }

    float bv[4];
#pragma unroll
    for (int j = 0; j < 4; ++j) bv[j] = bias[n0 + wcol + j * 16 + l16];

#pragma unroll
    for (int i = 0; i < 4; ++i) {
#pragma unroll
        for (int r = 0; r < 4; ++r) {
            const int row = m0 + wrow + i * 16 + quad * 4 + r;  // C/D: row=quad*4+reg
            float* crow = C + (size_t)row * N;
            if (INTERP) {
                const int lr3  = (row - m0) * 3;
                const int base = (row >> 14) * N_DOWN;          // batch * N_DOWN
                const float w0 = sV[lr3 + 0], w1 = sV[lr3 + 1], w2 = sV[lr3 + 2];
                const float* f0 = down_f + (size_t)(base + sI[lr3 + 0]) * N;
                const float* f1 = down_f + (size_t)(base + sI[lr3 + 1]) * N;
                const float* f2 = down_f + (size_t)(base + sI[lr3 + 2]) * N;
#pragma unroll
                for (int j = 0; j < 4; ++j) {
                    const int c = n0 + wcol + j * 16 + l16;     // C/D: col=lane&15
                    crow[c] = acc[i][j][r] + bv[j] + w0 * f0[c] + w1 * f1[c] + w2 * f2[c];
                }
            } else {
#pragma unroll
                for (int j = 0; j < 4; ++j) {
                    const int c = n0 + wcol + j * 16 + l16;
                    crow[c] = acc[i][j][r] + bv[j];
                }
            }
        }
    }
}

// ---------------------------------------------------------------------------
extern "C" void kernel_launch(void* const* d_in, const int* in_sizes, int n_in,
                              void* d_out, int out_size, void* d_ws, size_t ws_size,
                              hipStream_t stream) {
    const float* up_points     = (const float*)d_in[0];
    const float* up_features   = (const float*)d_in[1];
    const float* down_points   = (const float*)d_in[2];
    const float* down_features = (const float*)d_in[3];
    const float* W_up          = (const float*)d_in[4];
    const float* b_up          = (const float*)d_in[5];
    const float* W_down        = (const float*)d_in[6];
    const float* b_down        = (const float*)d_in[7];
    float* out = (float*)d_out;

    // workspace layout (all offsets 256B-aligned by construction)
    char* ws = (char*)d_ws;
    size_t off = 0;
    float* down_f = (float*)(ws + off);             off += (size_t)B_ * N_DOWN * C_OUT_ * 4;      // 33.6 MB
    int*   knn_idx = (int*)(ws + off);              off += (size_t)B_ * N_UP * 3 * 4;             // 0.8 MB
    float* knn_w   = (float*)(ws + off);            off += (size_t)B_ * N_UP * 3 * 4;             // 0.8 MB
    float* part_d  = (float*)(ws + off);            off += (size_t)B_ * N_UP * S_CHUNKS * 3 * 4;  // 12.6 MB
    int*   part_i  = (int*)(ws + off);              off += (size_t)B_ * N_UP * S_CHUNKS * 3 * 4;  // 12.6 MB
    float4* pts4   = (float4*)(ws + off);           off += (size_t)B_ * N_DOWN * 16;              // 0.26 MB
    unsigned short* upf_bf = (unsigned short*)(ws + off); off += (size_t)B_ * N_UP * C_UP_ * 2;   // 50.3 MB
    unsigned short* dnf_bf = (unsigned short*)(ws + off); off += (size_t)B_ * N_DOWN * C_DOWN_ * 2; // 16.8 MB
    unsigned short* wup_bf = (unsigned short*)(ws + off); off += (size_t)C_OUT_ * C_UP_ * 2;      // 0.4 MB
    unsigned short* wdn_bf = (unsigned short*)(ws + off); off += (size_t)C_OUT_ * C_DOWN_ * 2;    // 0.5 MB

    // 1) KNN pipeline
    prep_pts4<<<(B_ * N_DOWN) / 256, 256, 0, stream>>>(down_points, pts4);
    knn_chunk<<<dim3(N_UP / 512, B_, S_CHUNKS), 256, 0, stream>>>(
        up_points, pts4, part_d, part_i);
    knn_merge<<<(B_ * N_UP) / 256, 256, 0, stream>>>(part_d, part_i, knn_idx, knn_w);

    // 2) f32 -> bf16 conversions
    cvt_bf16<<<(B_ * N_UP * C_UP_) / 1024, 256, 0, stream>>>(up_features, upf_bf);
    cvt_bf16<<<(B_ * N_DOWN * C_DOWN_) / 1024, 256, 0, stream>>>(down_features, dnf_bf);
    cvt_bf16<<<(C_OUT_ * C_UP_) / 1024, 256, 0, stream>>>(W_up, wup_bf);
    cvt_bf16<<<(C_OUT_ * C_DOWN_) / 1024, 256, 0, stream>>>(W_down, wdn_bf);

    // 3) down_f = down_features @ W_down^T + b_down   [B*N_DOWN, 512]
    gemm_bf16<false><<<dim3(C_OUT_ / 128, (B_ * N_DOWN) / 128), 256, 0, stream>>>(
        dnf_bf, wdn_bf, b_down, down_f, C_DOWN_, C_OUT_, nullptr, nullptr, nullptr);

    // 4) out = up_features @ W_up^T + b_up + interp(down_f)   [B*N_UP, 512]
    gemm_bf16<true><<<dim3(C_OUT_ / 128, (B_ * N_UP) / 128), 256, 0, stream>>>(
        upf_bf, wup_bf, b_up, out, C_UP_, C_OUT_, knn_idx, knn_w, down_f);
}

// Round 6
// 458.518 us; speedup vs baseline: 1.0145x; 1.0145x over previous
//
#include <hip/hip_runtime.h>

// Problem constants (from reference)
constexpr int B_     = 4;
constexpr int N_UP   = 16384;
constexpr int N_DOWN = 4096;
constexpr int C_UP_  = 384;
constexpr int C_DOWN_= 512;
constexpr int C_OUT_ = 512;

// KNN chunking
constexpr int S_CHUNKS = 16;               // candidate chunks
constexpr int CH       = N_DOWN / S_CHUNKS; // 256 candidates per chunk

typedef __attribute__((ext_vector_type(8))) short bf16x8;
typedef __attribute__((ext_vector_type(4))) float f32x4;
typedef __attribute__((ext_vector_type(4))) float f4v;

// f32 -> bf16 round-to-nearest-even (bit-exact, no API dependence)
__device__ inline unsigned short f2bf(float f) {
    unsigned int u = __float_as_uint(f);
    return (unsigned short)((u + 0x7FFFu + ((u >> 16) & 1u)) >> 16);
}

// async global->LDS, 16B per lane. HW: dest = wave-uniform base + lane*16,
// so lds must be computed as base + lane*16 in lane order (it is, below).
__device__ inline void load_lds_128(const void* g, void* l) {
    __builtin_amdgcn_global_load_lds(
        (const __attribute__((address_space(1))) unsigned int*)g,
        (__attribute__((address_space(3))) unsigned int*)l, 16, 0, 0);
}

// ---------------------------------------------------------------------------
// pts4[b][m] = {x, y, z, (x*x+y*y)+z*z}   (ref rounding order, no contract)
// ---------------------------------------------------------------------------
__global__ void prep_pts4(const float* __restrict__ down_pts, float4* __restrict__ pts4) {
#pragma clang fp contract(off)
    const int i = blockIdx.x * 256 + threadIdx.x;   // 0 .. B*N_DOWN-1
    const float x = down_pts[i * 3 + 0];
    const float y = down_pts[i * 3 + 1];
    const float z = down_pts[i * 3 + 2];
    float4 p; p.x = x; p.y = y; p.z = z; p.w = (x * x + y * y) + z * z;
    pts4[i] = p;
}

// ---------------------------------------------------------------------------
// Per-chunk exact top-3 (R5 version — locally converged at 134 us; three
// structurally different inner loops all measured 134, pipe-model exhausted).
// ---------------------------------------------------------------------------
__launch_bounds__(256, 8)
__global__ void knn_chunk(const float* __restrict__ up_pts,   // [B,N_UP,3]
                          const float4* __restrict__ pts4,    // [B,N_DOWN]
                          float* __restrict__ part_d,         // [B*N_UP, S*3]
                          int*   __restrict__ part_i)
{
#pragma clang fp contract(off)
    const int b = blockIdx.y;
    const int s = blockIdx.z;
    const int mbase = s * CH;

    typedef __attribute__((address_space(4))) const f4v cst_f4;
    const cst_f4* sp = (const cst_f4*)(pts4 + (size_t)b * N_DOWN + mbase);

    const int n0 = blockIdx.x * 512;
    const int g0 = b * N_UP + n0 + threadIdx.x;
    const int g1 = g0 + 256;

    const float ax = up_pts[(size_t)g0 * 3 + 0];
    const float ay = up_pts[(size_t)g0 * 3 + 1];
    const float az = up_pts[(size_t)g0 * 3 + 2];
    const float au = (ax * ax + ay * ay) + az * az;
    const float bx = up_pts[(size_t)g1 * 3 + 0];
    const float by = up_pts[(size_t)g1 * 3 + 1];
    const float bz = up_pts[(size_t)g1 * 3 + 2];
    const float bu = (bx * bx + by * by) + bz * bz;

    float a0 = 1e30f, a1 = 1e30f, a2 = 1e30f;  int ia0 = 0, ia1 = 0, ia2 = 0;
    float b0 = 1e30f, b1 = 1e30f, b2 = 1e30f;  int ib0 = 0, ib1 = 0, ib2 = 0;

    // prefetch double-buffer: group of 4 candidates = 64B scalar load
    f4v c0 = sp[0], c1 = sp[1], c2 = sp[2], c3 = sp[3];

#define PAIR(P, GI)                                                        \
    {                                                                      \
        const float cra = (ax * (P).x + ay * (P).y) + az * (P).z;          \
        const float da  = __builtin_fmaf(-2.0f, cra, au + (P).w);          \
        const bool ca2 = da < a2, ca1 = da < a1, ca0 = da < a0;            \
        { const int t = ca2 ? (GI) : ia2; ia2 = ca1 ? ia1 : t; }           \
        { const int t = ca1 ? (GI) : ia1; ia1 = ca0 ? ia0 : t; }           \
        ia0 = ca0 ? (GI) : ia0;                                            \
        const float na1 = __builtin_amdgcn_fmed3f(da, a0, a1);             \
        const float na2 = __builtin_amdgcn_fmed3f(da, a1, a2);             \
        a0 = fminf(a0, da); a1 = na1; a2 = na2;                            \
        const float crb = (bx * (P).x + by * (P).y) + bz * (P).z;          \
        const float db  = __builtin_fmaf(-2.0f, crb, bu + (P).w);          \
        const bool cb2 = db < b2, cb1 = db < b1, cb0 = db < b0;            \
        { const int t = cb2 ? (GI) : ib2; ib2 = cb1 ? ib1 : t; }           \
        { const int t = cb1 ? (GI) : ib1; ib1 = cb0 ? ib0 : t; }           \
        ib0 = cb0 ? (GI) : ib0;                                            \
        const float nb1 = __builtin_amdgcn_fmed3f(db, b0, b1);             \
        const float nb2 = __builtin_amdgcn_fmed3f(db, b1, b2);             \
        b0 = fminf(b0, db); b1 = nb1; b2 = nb2;                            \
    }

#pragma unroll 1
    for (int mg = 0; mg < CH; mg += 4) {
        const int nx = (mg + 4 < CH) ? (mg + 4) : 0;
        const f4v p0 = sp[nx], p1 = sp[nx + 1], p2 = sp[nx + 2], p3 = sp[nx + 3];
        PAIR(c0, mbase + mg + 0);
        PAIR(c1, mbase + mg + 1);
        PAIR(c2, mbase + mg + 2);
        PAIR(c3, mbase + mg + 3);
        c0 = p0; c1 = p1; c2 = p2; c3 = p3;
    }
#undef PAIR

    float* pd = part_d + (size_t)g0 * (S_CHUNKS * 3) + s * 3;
    int*   pi = part_i + (size_t)g0 * (S_CHUNKS * 3) + s * 3;
    pd[0] = a0; pd[1] = a1; pd[2] = a2;
    pi[0] = ia0; pi[1] = ia1; pi[2] = ia2;
    pd = part_d + (size_t)g1 * (S_CHUNKS * 3) + s * 3;
    pi = part_i + (size_t)g1 * (S_CHUNKS * 3) + s * 3;
    pd[0] = b0; pd[1] = b1; pd[2] = b2;
    pi[0] = ib0; pi[1] = ib1; pi[2] = ib2;
}

// ---------------------------------------------------------------------------
// Merge S*3 exact candidates (ascending chunk = ascending index => identical
// tie-breaks to the full scan), compute normalized inverse-distance weights.
// ---------------------------------------------------------------------------
__launch_bounds__(256)
__global__ void knn_merge(const float* __restrict__ part_d,
                          const int*   __restrict__ part_i,
                          int*  __restrict__ idx_out,   // [B*N_UP,3]
                          float* __restrict__ w_out)    // [B*N_UP,3]
{
    const int g = blockIdx.x * 256 + threadIdx.x;
    const float4* pd = (const float4*)(part_d + (size_t)g * (S_CHUNKS * 3));
    const int4*   pi = (const int4*)(part_i + (size_t)g * (S_CHUNKS * 3));

    float d0 = 1e30f, d1 = 1e30f, d2 = 1e30f;
    int   i0 = 0,     i1 = 0,     i2 = 0;

#pragma unroll
    for (int q = 0; q < (S_CHUNKS * 3) / 4; ++q) {
        const float4 dv = pd[q];
        const int4   iv = pi[q];
        const float dd[4] = {dv.x, dv.y, dv.z, dv.w};
        const int   ii[4] = {iv.x, iv.y, iv.z, iv.w};
#pragma unroll
        for (int j = 0; j < 4; ++j) {
            const float d = dd[j];
            const int   m = ii[j];
            const bool c2 = d < d2;
            const bool c1 = d < d1;
            const bool c0 = d < d0;
            { const int t = c2 ? m : i2; i2 = c1 ? i1 : t; }
            { const int t = c1 ? m : i1; i1 = c0 ? i0 : t; }
            i0 = c0 ? m : i0;
            const float nd1 = __builtin_amdgcn_fmed3f(d, d0, d1);
            const float nd2 = __builtin_amdgcn_fmed3f(d, d1, d2);
            d0 = fminf(d0, d);
            d1 = nd1;
            d2 = nd2;
        }
    }

    const float w0 = 1.0f / (d0 + 1e-8f);
    const float w1 = 1.0f / (d1 + 1e-8f);
    const float w2 = 1.0f / (d2 + 1e-8f);
    const float s  = (w0 + w1) + w2;
    idx_out[(size_t)g * 3 + 0] = i0;
    idx_out[(size_t)g * 3 + 1] = i1;
    idx_out[(size_t)g * 3 + 2] = i2;
    w_out[(size_t)g * 3 + 0] = w0 / s;
    w_out[(size_t)g * 3 + 1] = w1 / s;
    w_out[(size_t)g * 3 + 2] = w2 / s;
}

// ---------------------------------------------------------------------------
// Fused f32 -> bf16 conversion for all 4 buffers in ONE dispatch.
// Block ranges (1024 elements/block): [0,24576) upf | [24576,32768) dnf |
// [32768,32960) wup | [32960,33216) wdn.  Branch is block-uniform.
// ---------------------------------------------------------------------------
__launch_bounds__(256)
__global__ void cvt_all(const float* __restrict__ s_upf, unsigned short* __restrict__ d_upf,
                        const float* __restrict__ s_dnf, unsigned short* __restrict__ d_dnf,
                        const float* __restrict__ s_wup, unsigned short* __restrict__ d_wup,
                        const float* __restrict__ s_wdn, unsigned short* __restrict__ d_wdn)
{
    const int blk = blockIdx.x;
    const float* s; unsigned short* d; size_t base;
    if (blk < 24576)      { s = s_upf; d = d_upf; base = (size_t)blk * 1024; }
    else if (blk < 32768) { s = s_dnf; d = d_dnf; base = (size_t)(blk - 24576) * 1024; }
    else if (blk < 32960) { s = s_wup; d = d_wup; base = (size_t)(blk - 32768) * 1024; }
    else                  { s = s_wdn; d = d_wdn; base = (size_t)(blk - 32960) * 1024; }
    const size_t i = base / 4 + threadIdx.x;   // float4 index
    const float4 v = ((const float4*)s)[i];
    ushort4 o;
    o.x = f2bf(v.x); o.y = f2bf(v.y); o.z = f2bf(v.z); o.w = f2bf(v.w);
    ((ushort4*)d)[i] = o;
}

// ---------------------------------------------------------------------------
// bf16 MFMA GEMM: C[m,n] = sum_k A[m,k]*W[n,k] (+bias) (+interp gather)
// 128x128 tile, BK=64 (halves the 2-phase stage/vmcnt/barrier events vs
// BK=32 -- m233: that path is ~72% of a 2ph iteration), 256 threads =
// 4 waves (2x2 of 64x64), 16x16x32 MFMA, width-16 global_load_lds staging.
// LDS 2x16KB -> 4-5 blocks/CU (avoids m132's BK=128 occupancy cliff).
// ---------------------------------------------------------------------------
template<bool INTERP>
__launch_bounds__(256)
__global__ void gemm_bf16(const unsigned short* __restrict__ A,  // [M,K] bf16
                          const unsigned short* __restrict__ W,  // [N,K] bf16
                          const float* __restrict__ bias,        // [N]
                          float* __restrict__ C,                 // [M,N] f32
                          const int K, const int N,
                          const int* __restrict__ knn_idx,       // [M,3]
                          const float* __restrict__ knn_w,       // [M,3]
                          const float* __restrict__ down_f)      // [B*N_DOWN,N]
{
    __shared__ __align__(16) unsigned short As[128 * 64];   // 16 KB
    __shared__ __align__(16) unsigned short Bs[128 * 64];   // 16 KB
    __shared__ int   sI[128 * 3];
    __shared__ float sV[128 * 3];

    const int tid  = threadIdx.x;
    const int lane = tid & 63;
    const int wv   = tid >> 6;
    const int wrow = (wv >> 1) * 64;
    const int wcol = (wv & 1) * 64;
    const int quad = lane >> 4;
    const int l16  = lane & 15;
    const int m0   = blockIdx.y * 128;
    const int n0   = blockIdx.x * 128;

    if (INTERP) {
        for (int t = tid; t < 384; t += 256) {
            sI[t] = knn_idx[(size_t)m0 * 3 + t];
            sV[t] = knn_w[(size_t)m0 * 3 + t];
        }
    }

    f32x4 acc[4][4];
#pragma unroll
    for (int i = 0; i < 4; ++i)
#pragma unroll
        for (int j = 0; j < 4; ++j) {
            acc[i][j][0] = 0.f; acc[i][j][1] = 0.f;
            acc[i][j][2] = 0.f; acc[i][j][3] = 0.f;
        }

    // staging geometry: LDS tile is [row][64k] bf16 (128 B rows); each wave
    // covers 4 KiB (32 rows) as four 1 KiB chunks of lane*16.
    const int o0 = wv * 4096 + lane * 16;
    const char* Ab = (const char*)A;
    const char* Wb = (const char*)W;
    const size_t Ks = (size_t)K;

    for (int k0 = 0; k0 < K; k0 += 64) {
        __syncthreads();   // previous iter's ds_reads done before overwrite
#pragma unroll
        for (int c = 0; c < 4; ++c) {
            const int o = o0 + c * 1024;
            const int r = o >> 7, kb = o & 127;
            load_lds_128(Ab + ((size_t)(m0 + r) * Ks + k0) * 2 + kb, (char*)As + o);
            load_lds_128(Wb + ((size_t)(n0 + r) * Ks + k0) * 2 + kb, (char*)Bs + o);
        }
        __syncthreads();   // vmcnt(0) drained by compiler before barrier

#pragma unroll
        for (int kk = 0; kk < 2; ++kk) {
            bf16x8 af[4], bw[4];
#pragma unroll
            for (int i = 0; i < 4; ++i)
                af[i] = *(const bf16x8*)(As + (wrow + i * 16 + l16) * 64 + kk * 32 + quad * 8);
#pragma unroll
            for (int j = 0; j < 4; ++j)
                bw[j] = *(const bf16x8*)(Bs + (wcol + j * 16 + l16) * 64 + kk * 32 + quad * 8);
#pragma unroll
            for (int i = 0; i < 4; ++i)
#pragma unroll
                for (int j = 0; j < 4; ++j)
                    acc[i][j] = __builtin_amdgcn_mfma_f32_16x16x32_bf16(
                        af[i], bw[j], acc[i][j], 0, 0, 0);
        }
    }

    float bv[4];
#pragma unroll
    for (int j = 0; j < 4; ++j) bv[j] = bias[n0 + wcol + j * 16 + l16];

#pragma unroll
    for (int i = 0; i < 4; ++i) {
#pragma unroll
        for (int r = 0; r < 4; ++r) {
            const int row = m0 + wrow + i * 16 + quad * 4 + r;  // C/D: row=quad*4+reg
            float* crow = C + (size_t)row * N;
            if (INTERP) {
                const int lr3  = (row - m0) * 3;
                const int base = (row >> 14) * N_DOWN;          // batch * N_DOWN
                const float w0 = sV[lr3 + 0], w1 = sV[lr3 + 1], w2 = sV[lr3 + 2];
                const float* f0 = down_f + (size_t)(base + sI[lr3 + 0]) * N;
                const float* f1 = down_f + (size_t)(base + sI[lr3 + 1]) * N;
                const float* f2 = down_f + (size_t)(base + sI[lr3 + 2]) * N;
#pragma unroll
                for (int j = 0; j < 4; ++j) {
                    const int c = n0 + wcol + j * 16 + l16;     // C/D: col=lane&15
                    crow[c] = acc[i][j][r] + bv[j] + w0 * f0[c] + w1 * f1[c] + w2 * f2[c];
                }
            } else {
#pragma unroll
                for (int j = 0; j < 4; ++j) {
                    const int c = n0 + wcol + j * 16 + l16;
                    crow[c] = acc[i][j][r] + bv[j];
                }
            }
        }
    }
}

// ---------------------------------------------------------------------------
extern "C" void kernel_launch(void* const* d_in, const int* in_sizes, int n_in,
                              void* d_out, int out_size, void* d_ws, size_t ws_size,
                              hipStream_t stream) {
    const float* up_points     = (const float*)d_in[0];
    const float* up_features   = (const float*)d_in[1];
    const float* down_points   = (const float*)d_in[2];
    const float* down_features = (const float*)d_in[3];
    const float* W_up          = (const float*)d_in[4];
    const float* b_up          = (const float*)d_in[5];
    const float* W_down        = (const float*)d_in[6];
    const float* b_down        = (const float*)d_in[7];
    float* out = (float*)d_out;

    // workspace layout (all offsets 256B-aligned by construction)
    char* ws = (char*)d_ws;
    size_t off = 0;
    float* down_f = (float*)(ws + off);             off += (size_t)B_ * N_DOWN * C_OUT_ * 4;      // 33.6 MB
    int*   knn_idx = (int*)(ws + off);              off += (size_t)B_ * N_UP * 3 * 4;             // 0.8 MB
    float* knn_w   = (float*)(ws + off);            off += (size_t)B_ * N_UP * 3 * 4;             // 0.8 MB
    float* part_d  = (float*)(ws + off);            off += (size_t)B_ * N_UP * S_CHUNKS * 3 * 4;  // 12.6 MB
    int*   part_i  = (int*)(ws + off);              off += (size_t)B_ * N_UP * S_CHUNKS * 3 * 4;  // 12.6 MB
    float4* pts4   = (float4*)(ws + off);           off += (size_t)B_ * N_DOWN * 16;              // 0.26 MB
    unsigned short* upf_bf = (unsigned short*)(ws + off); off += (size_t)B_ * N_UP * C_UP_ * 2;   // 50.3 MB
    unsigned short* dnf_bf = (unsigned short*)(ws + off); off += (size_t)B_ * N_DOWN * C_DOWN_ * 2; // 16.8 MB
    unsigned short* wup_bf = (unsigned short*)(ws + off); off += (size_t)C_OUT_ * C_UP_ * 2;      // 0.4 MB
    unsigned short* wdn_bf = (unsigned short*)(ws + off); off += (size_t)C_OUT_ * C_DOWN_ * 2;    // 0.5 MB

    // 1) KNN pipeline
    prep_pts4<<<(B_ * N_DOWN) / 256, 256, 0, stream>>>(down_points, pts4);
    knn_chunk<<<dim3(N_UP / 512, B_, S_CHUNKS), 256, 0, stream>>>(
        up_points, pts4, part_d, part_i);
    knn_merge<<<(B_ * N_UP) / 256, 256, 0, stream>>>(part_d, part_i, knn_idx, knn_w);

    // 2) fused f32 -> bf16 conversion (upf 24576 + dnf 8192 + wup 192 + wdn 256
    //    blocks of 1024 elements each = 33216 blocks)
    cvt_all<<<33216, 256, 0, stream>>>(up_features, upf_bf, down_features, dnf_bf,
                                       W_up, wup_bf, W_down, wdn_bf);

    // 3) down_f = down_features @ W_down^T + b_down   [B*N_DOWN, 512]
    gemm_bf16<false><<<dim3(C_OUT_ / 128, (B_ * N_DOWN) / 128), 256, 0, stream>>>(
        dnf_bf, wdn_bf, b_down, down_f, C_DOWN_, C_OUT_, nullptr, nullptr, nullptr);

    // 4) out = up_features @ W_up^T + b_up + interp(down_f)   [B*N_UP, 512]
    gemm_bf16<true><<<dim3(C_OUT_ / 128, (B_ * N_UP) / 128), 256, 0, stream>>>(
        upf_bf, wup_bf, b_up, out, C_UP_, C_OUT_, knn_idx, knn_w, down_f);
}

// Round 7
// 433.703 us; speedup vs baseline: 1.0726x; 1.0572x over previous
//
#include <hip/hip_runtime.h>

// Problem constants (from reference)
constexpr int B_     = 4;
constexpr int N_UP   = 16384;
constexpr int N_DOWN = 4096;
constexpr int C_UP_  = 384;
constexpr int C_DOWN_= 512;
constexpr int C_OUT_ = 512;

// KNN chunking
constexpr int S_CHUNKS = 16;               // candidate chunks
constexpr int CH       = N_DOWN / S_CHUNKS; // 256 candidates per chunk

// Fused phase-1 dispatch geometry (knn half + cvt half per dispatch)
constexpr int KNN_BLOCKS_HALF = (N_UP / 512) * B_ * (S_CHUNKS / 2);  // 1024
constexpr int CVT_BLOCKS_TOT  = 24576 + 8192 + 192 + 256;            // 33216
constexpr int CVT_BLOCKS_HALF = CVT_BLOCKS_TOT / 2;                  // 16608

typedef __attribute__((ext_vector_type(8))) short bf16x8;
typedef __attribute__((ext_vector_type(4))) float f32x4;
typedef __attribute__((ext_vector_type(4))) float f4v;

// f32 -> bf16 round-to-nearest-even (bit-exact, no API dependence)
__device__ inline unsigned short f2bf(float f) {
    unsigned int u = __float_as_uint(f);
    return (unsigned short)((u + 0x7FFFu + ((u >> 16) & 1u)) >> 16);
}

// async global->LDS, 16B per lane. HW: dest = wave-uniform base + lane*16,
// so lds must be computed as base + lane*16 in lane order (it is, below).
__device__ inline void load_lds_128(const void* g, void* l) {
    __builtin_amdgcn_global_load_lds(
        (const __attribute__((address_space(1))) unsigned int*)g,
        (__attribute__((address_space(3))) unsigned int*)l, 16, 0, 0);
}

// ---------------------------------------------------------------------------
// pts4[b][m] = {x, y, z, (x*x+y*y)+z*z}   (ref rounding order, no contract)
// ---------------------------------------------------------------------------
__global__ void prep_pts4(const float* __restrict__ down_pts, float4* __restrict__ pts4) {
#pragma clang fp contract(off)
    const int i = blockIdx.x * 256 + threadIdx.x;   // 0 .. B*N_DOWN-1
    const float x = down_pts[i * 3 + 0];
    const float y = down_pts[i * 3 + 1];
    const float z = down_pts[i * 3 + 2];
    float4 p; p.x = x; p.y = y; p.z = z; p.w = (x * x + y * y) + z * z;
    pts4[i] = p;
}

// ---------------------------------------------------------------------------
// FUSED phase-1: knn chunk scan (blocks [0,1024)) + f32->bf16 cvt (rest).
// The two paths are fully independent (no shared state, no sync); cvt blocks
// backfill CU slots as knn blocks drain, hiding cvt's ~200MB HBM stream in
// knn's issue-latency shadow. Launched TWICE (s_base 0/8, cvt_base 0/16608)
// so each instance is ~half duration -> anything >=90us elsewhere surfaces
// in the top-5 profile next round.
//
// knn body is byte-identical to the R5/R6 passing version (locally converged
// at 134us over three structural rewrites). cvt body identical to R6.
// ---------------------------------------------------------------------------
__launch_bounds__(256, 8)
__global__ void knn_cvt(const float* __restrict__ up_pts,   // [B,N_UP,3]
                        const float4* __restrict__ pts4,    // [B,N_DOWN]
                        float* __restrict__ part_d,         // [B*N_UP, S*3]
                        int*   __restrict__ part_i,
                        const int s_base, const int cvt_base,
                        const float* __restrict__ s_upf, unsigned short* __restrict__ d_upf,
                        const float* __restrict__ s_dnf, unsigned short* __restrict__ d_dnf,
                        const float* __restrict__ s_wup, unsigned short* __restrict__ d_wup,
                        const float* __restrict__ s_wdn, unsigned short* __restrict__ d_wdn)
{
    if (blockIdx.x < KNN_BLOCKS_HALF) {
#pragma clang fp contract(off)
        const int kb = blockIdx.x;
        const int b  = (kb >> 5) & 3;
        const int s  = s_base + (kb >> 7);
        const int mbase = s * CH;

        typedef __attribute__((address_space(4))) const f4v cst_f4;
        const cst_f4* sp = (const cst_f4*)(pts4 + (size_t)b * N_DOWN + mbase);

        const int n0 = (kb & 31) * 512;
        const int g0 = b * N_UP + n0 + threadIdx.x;
        const int g1 = g0 + 256;

        const float ax = up_pts[(size_t)g0 * 3 + 0];
        const float ay = up_pts[(size_t)g0 * 3 + 1];
        const float az = up_pts[(size_t)g0 * 3 + 2];
        const float au = (ax * ax + ay * ay) + az * az;
        const float bx = up_pts[(size_t)g1 * 3 + 0];
        const float by = up_pts[(size_t)g1 * 3 + 1];
        const float bz = up_pts[(size_t)g1 * 3 + 2];
        const float bu = (bx * bx + by * by) + bz * bz;

        float a0 = 1e30f, a1 = 1e30f, a2 = 1e30f;  int ia0 = 0, ia1 = 0, ia2 = 0;
        float b0 = 1e30f, b1 = 1e30f, b2 = 1e30f;  int ib0 = 0, ib1 = 0, ib2 = 0;

        // prefetch double-buffer: group of 4 candidates = 64B scalar load
        f4v c0 = sp[0], c1 = sp[1], c2 = sp[2], c3 = sp[3];

#define PAIR(P, GI)                                                        \
        {                                                                  \
            const float cra = (ax * (P).x + ay * (P).y) + az * (P).z;      \
            const float da  = __builtin_fmaf(-2.0f, cra, au + (P).w);      \
            const bool ca2 = da < a2, ca1 = da < a1, ca0 = da < a0;        \
            { const int t = ca2 ? (GI) : ia2; ia2 = ca1 ? ia1 : t; }       \
            { const int t = ca1 ? (GI) : ia1; ia1 = ca0 ? ia0 : t; }       \
            ia0 = ca0 ? (GI) : ia0;                                        \
            const float na1 = __builtin_amdgcn_fmed3f(da, a0, a1);         \
            const float na2 = __builtin_amdgcn_fmed3f(da, a1, a2);         \
            a0 = fminf(a0, da); a1 = na1; a2 = na2;                        \
            const float crb = (bx * (P).x + by * (P).y) + bz * (P).z;      \
            const float db  = __builtin_fmaf(-2.0f, crb, bu + (P).w);      \
            const bool cb2 = db < b2, cb1 = db < b1, cb0 = db < b0;        \
            { const int t = cb2 ? (GI) : ib2; ib2 = cb1 ? ib1 : t; }       \
            { const int t = cb1 ? (GI) : ib1; ib1 = cb0 ? ib0 : t; }       \
            ib0 = cb0 ? (GI) : ib0;                                        \
            const float nb1 = __builtin_amdgcn_fmed3f(db, b0, b1);         \
            const float nb2 = __builtin_amdgcn_fmed3f(db, b1, b2);         \
            b0 = fminf(b0, db); b1 = nb1; b2 = nb2;                        \
        }

#pragma unroll 1
        for (int mg = 0; mg < CH; mg += 4) {
            const int nx = (mg + 4 < CH) ? (mg + 4) : 0;
            const f4v p0 = sp[nx], p1 = sp[nx + 1], p2 = sp[nx + 2], p3 = sp[nx + 3];
            PAIR(c0, mbase + mg + 0);
            PAIR(c1, mbase + mg + 1);
            PAIR(c2, mbase + mg + 2);
            PAIR(c3, mbase + mg + 3);
            c0 = p0; c1 = p1; c2 = p2; c3 = p3;
        }
#undef PAIR

        float* pd = part_d + (size_t)g0 * (S_CHUNKS * 3) + s * 3;
        int*   pi = part_i + (size_t)g0 * (S_CHUNKS * 3) + s * 3;
        pd[0] = a0; pd[1] = a1; pd[2] = a2;
        pi[0] = ia0; pi[1] = ia1; pi[2] = ia2;
        pd = part_d + (size_t)g1 * (S_CHUNKS * 3) + s * 3;
        pi = part_i + (size_t)g1 * (S_CHUNKS * 3) + s * 3;
        pd[0] = b0; pd[1] = b1; pd[2] = b2;
        pi[0] = ib0; pi[1] = ib1; pi[2] = ib2;
    } else {
        // cvt path: 1024 f32 elements per block, block-uniform buffer select
        const int blk = blockIdx.x - KNN_BLOCKS_HALF + cvt_base;
        const float* s; unsigned short* d; size_t base;
        if (blk < 24576)      { s = s_upf; d = d_upf; base = (size_t)blk * 1024; }
        else if (blk < 32768) { s = s_dnf; d = d_dnf; base = (size_t)(blk - 24576) * 1024; }
        else if (blk < 32960) { s = s_wup; d = d_wup; base = (size_t)(blk - 32768) * 1024; }
        else                  { s = s_wdn; d = d_wdn; base = (size_t)(blk - 32960) * 1024; }
        const size_t i = base / 4 + threadIdx.x;   // float4 index
        const float4 v = ((const float4*)s)[i];
        ushort4 o;
        o.x = f2bf(v.x); o.y = f2bf(v.y); o.z = f2bf(v.z); o.w = f2bf(v.w);
        ((ushort4*)d)[i] = o;
    }
}

// ---------------------------------------------------------------------------
// Merge S*3 exact candidates (ascending chunk = ascending index => identical
// tie-breaks to the full scan), compute normalized inverse-distance weights.
// ---------------------------------------------------------------------------
__launch_bounds__(256)
__global__ void knn_merge(const float* __restrict__ part_d,
                          const int*   __restrict__ part_i,
                          int*  __restrict__ idx_out,   // [B*N_UP,3]
                          float* __restrict__ w_out)    // [B*N_UP,3]
{
    const int g = blockIdx.x * 256 + threadIdx.x;
    const float4* pd = (const float4*)(part_d + (size_t)g * (S_CHUNKS * 3));
    const int4*   pi = (const int4*)(part_i + (size_t)g * (S_CHUNKS * 3));

    float d0 = 1e30f, d1 = 1e30f, d2 = 1e30f;
    int   i0 = 0,     i1 = 0,     i2 = 0;

#pragma unroll
    for (int q = 0; q < (S_CHUNKS * 3) / 4; ++q) {
        const float4 dv = pd[q];
        const int4   iv = pi[q];
        const float dd[4] = {dv.x, dv.y, dv.z, dv.w};
        const int   ii[4] = {iv.x, iv.y, iv.z, iv.w};
#pragma unroll
        for (int j = 0; j < 4; ++j) {
            const float d = dd[j];
            const int   m = ii[j];
            const bool c2 = d < d2;
            const bool c1 = d < d1;
            const bool c0 = d < d0;
            { const int t = c2 ? m : i2; i2 = c1 ? i1 : t; }
            { const int t = c1 ? m : i1; i1 = c0 ? i0 : t; }
            i0 = c0 ? m : i0;
            const float nd1 = __builtin_amdgcn_fmed3f(d, d0, d1);
            const float nd2 = __builtin_amdgcn_fmed3f(d, d1, d2);
            d0 = fminf(d0, d);
            d1 = nd1;
            d2 = nd2;
        }
    }

    const float w0 = 1.0f / (d0 + 1e-8f);
    const float w1 = 1.0f / (d1 + 1e-8f);
    const float w2 = 1.0f / (d2 + 1e-8f);
    const float s  = (w0 + w1) + w2;
    idx_out[(size_t)g * 3 + 0] = i0;
    idx_out[(size_t)g * 3 + 1] = i1;
    idx_out[(size_t)g * 3 + 2] = i2;
    w_out[(size_t)g * 3 + 0] = w0 / s;
    w_out[(size_t)g * 3 + 1] = w1 / s;
    w_out[(size_t)g * 3 + 2] = w2 / s;
}

// ---------------------------------------------------------------------------
// bf16 MFMA GEMM: C[m,n] = sum_k A[m,k]*W[n,k] (+bias) (+interp gather)
// 128x128 tile, BK=64, 256 threads = 4 waves (2x2 of 64x64), 16x16x32 MFMA,
// width-16 global_load_lds staging.
// ---------------------------------------------------------------------------
template<bool INTERP>
__launch_bounds__(256)
__global__ void gemm_bf16(const unsigned short* __restrict__ A,  // [M,K] bf16
                          const unsigned short* __restrict__ W,  // [N,K] bf16
                          const float* __restrict__ bias,        // [N]
                          float* __restrict__ C,                 // [M,N] f32
                          const int K, const int N,
                          const int* __restrict__ knn_idx,       // [M,3]
                          const float* __restrict__ knn_w,       // [M,3]
                          const float* __restrict__ down_f)      // [B*N_DOWN,N]
{
    __shared__ __align__(16) unsigned short As[128 * 64];   // 16 KB
    __shared__ __align__(16) unsigned short Bs[128 * 64];   // 16 KB
    __shared__ int   sI[128 * 3];
    __shared__ float sV[128 * 3];

    const int tid  = threadIdx.x;
    const int lane = tid & 63;
    const int wv   = tid >> 6;
    const int wrow = (wv >> 1) * 64;
    const int wcol = (wv & 1) * 64;
    const int quad = lane >> 4;
    const int l16  = lane & 15;
    const int m0   = blockIdx.y * 128;
    const int n0   = blockIdx.x * 128;

    if (INTERP) {
        for (int t = tid; t < 384; t += 256) {
            sI[t] = knn_idx[(size_t)m0 * 3 + t];
            sV[t] = knn_w[(size_t)m0 * 3 + t];
        }
    }

    f32x4 acc[4][4];
#pragma unroll
    for (int i = 0; i < 4; ++i)
#pragma unroll
        for (int j = 0; j < 4; ++j) {
            acc[i][j][0] = 0.f; acc[i][j][1] = 0.f;
            acc[i][j][2] = 0.f; acc[i][j][3] = 0.f;
        }

    // staging geometry: LDS tile is [row][64k] bf16 (128 B rows); each wave
    // covers 4 KiB (32 rows) as four 1 KiB chunks of lane*16.
    const int o0 = wv * 4096 + lane * 16;
    const char* Ab = (const char*)A;
    const char* Wb = (const char*)W;
    const size_t Ks = (size_t)K;

    for (int k0 = 0; k0 < K; k0 += 64) {
        __syncthreads();   // previous iter's ds_reads done before overwrite
#pragma unroll
        for (int c = 0; c < 4; ++c) {
            const int o = o0 + c * 1024;
            const int r = o >> 7, kb = o & 127;
            load_lds_128(Ab + ((size_t)(m0 + r) * Ks + k0) * 2 + kb, (char*)As + o);
            load_lds_128(Wb + ((size_t)(n0 + r) * Ks + k0) * 2 + kb, (char*)Bs + o);
        }
        __syncthreads();   // vmcnt(0) drained by compiler before barrier

#pragma unroll
        for (int kk = 0; kk < 2; ++kk) {
            bf16x8 af[4], bw[4];
#pragma unroll
            for (int i = 0; i < 4; ++i)
                af[i] = *(const bf16x8*)(As + (wrow + i * 16 + l16) * 64 + kk * 32 + quad * 8);
#pragma unroll
            for (int j = 0; j < 4; ++j)
                bw[j] = *(const bf16x8*)(Bs + (wcol + j * 16 + l16) * 64 + kk * 32 + quad * 8);
#pragma unroll
            for (int i = 0; i < 4; ++i)
#pragma unroll
                for (int j = 0; j < 4; ++j)
                    acc[i][j] = __builtin_amdgcn_mfma_f32_16x16x32_bf16(
                        af[i], bw[j], acc[i][j], 0, 0, 0);
        }
    }

    float bv[4];
#pragma unroll
    for (int j = 0; j < 4; ++j) bv[j] = bias[n0 + wcol + j * 16 + l16];

#pragma unroll
    for (int i = 0; i < 4; ++i) {
#pragma unroll
        for (int r = 0; r < 4; ++r) {
            const int row = m0 + wrow + i * 16 + quad * 4 + r;  // C/D: row=quad*4+reg
            float* crow = C + (size_t)row * N;
            if (INTERP) {
                const int lr3  = (row - m0) * 3;
                const int base = (row >> 14) * N_DOWN;          // batch * N_DOWN
                const float w0 = sV[lr3 + 0], w1 = sV[lr3 + 1], w2 = sV[lr3 + 2];
                const float* f0 = down_f + (size_t)(base + sI[lr3 + 0]) * N;
                const float* f1 = down_f + (size_t)(base + sI[lr3 + 1]) * N;
                const float* f2 = down_f + (size_t)(base + sI[lr3 + 2]) * N;
#pragma unroll
                for (int j = 0; j < 4; ++j) {
                    const int c = n0 + wcol + j * 16 + l16;     // C/D: col=lane&15
                    crow[c] = acc[i][j][r] + bv[j] + w0 * f0[c] + w1 * f1[c] + w2 * f2[c];
                }
            } else {
#pragma unroll
                for (int j = 0; j < 4; ++j) {
                    const int c = n0 + wcol + j * 16 + l16;
                    crow[c] = acc[i][j][r] + bv[j];
                }
            }
        }
    }
}

// ---------------------------------------------------------------------------
extern "C" void kernel_launch(void* const* d_in, const int* in_sizes, int n_in,
                              void* d_out, int out_size, void* d_ws, size_t ws_size,
                              hipStream_t stream) {
    const float* up_points     = (const float*)d_in[0];
    const float* up_features   = (const float*)d_in[1];
    const float* down_points   = (const float*)d_in[2];
    const float* down_features = (const float*)d_in[3];
    const float* W_up          = (const float*)d_in[4];
    const float* b_up          = (const float*)d_in[5];
    const float* W_down        = (const float*)d_in[6];
    const float* b_down        = (const float*)d_in[7];
    float* out = (float*)d_out;

    // workspace layout (all offsets 256B-aligned by construction)
    char* ws = (char*)d_ws;
    size_t off = 0;
    float* down_f = (float*)(ws + off);             off += (size_t)B_ * N_DOWN * C_OUT_ * 4;      // 33.6 MB
    int*   knn_idx = (int*)(ws + off);              off += (size_t)B_ * N_UP * 3 * 4;             // 0.8 MB
    float* knn_w   = (float*)(ws + off);            off += (size_t)B_ * N_UP * 3 * 4;             // 0.8 MB
    float* part_d  = (float*)(ws + off);            off += (size_t)B_ * N_UP * S_CHUNKS * 3 * 4;  // 12.6 MB
    int*   part_i  = (int*)(ws + off);              off += (size_t)B_ * N_UP * S_CHUNKS * 3 * 4;  // 12.6 MB
    float4* pts4   = (float4*)(ws + off);           off += (size_t)B_ * N_DOWN * 16;              // 0.26 MB
    unsigned short* upf_bf = (unsigned short*)(ws + off); off += (size_t)B_ * N_UP * C_UP_ * 2;   // 50.3 MB
    unsigned short* dnf_bf = (unsigned short*)(ws + off); off += (size_t)B_ * N_DOWN * C_DOWN_ * 2; // 16.8 MB
    unsigned short* wup_bf = (unsigned short*)(ws + off); off += (size_t)C_OUT_ * C_UP_ * 2;      // 0.4 MB
    unsigned short* wdn_bf = (unsigned short*)(ws + off); off += (size_t)C_OUT_ * C_DOWN_ * 2;    // 0.5 MB

    // 1) points prep
    prep_pts4<<<(B_ * N_DOWN) / 256, 256, 0, stream>>>(down_points, pts4);

    // 2) fused knn + cvt, two half-dispatches (S chunks 0-7 / 8-15; cvt blocks
    //    [0,16608) / [16608,33216)). Independent paths; cvt backfills knn.
    knn_cvt<<<KNN_BLOCKS_HALF + CVT_BLOCKS_HALF, 256, 0, stream>>>(
        up_points, pts4, part_d, part_i, 0, 0,
        up_features, upf_bf, down_features, dnf_bf, W_up, wup_bf, W_down, wdn_bf);
    knn_cvt<<<KNN_BLOCKS_HALF + CVT_BLOCKS_HALF, 256, 0, stream>>>(
        up_points, pts4, part_d, part_i, 8, CVT_BLOCKS_HALF,
        up_features, upf_bf, down_features, dnf_bf, W_up, wup_bf, W_down, wdn_bf);

    // 3) merge partial top-3s
    knn_merge<<<(B_ * N_UP) / 256, 256, 0, stream>>>(part_d, part_i, knn_idx, knn_w);

    // 4) down_f = down_features @ W_down^T + b_down   [B*N_DOWN, 512]
    gemm_bf16<false><<<dim3(C_OUT_ / 128, (B_ * N_DOWN) / 128), 256, 0, stream>>>(
        dnf_bf, wdn_bf, b_down, down_f, C_DOWN_, C_OUT_, nullptr, nullptr, nullptr);

    // 5) out = up_features @ W_up^T + b_up + interp(down_f)   [B*N_UP, 512]
    gemm_bf16<true><<<dim3(C_OUT_ / 128, (B_ * N_UP) / 128), 256, 0, stream>>>(
        upf_bf, wup_bf, b_up, out, C_UP_, C_OUT_, knn_idx, knn_w, down_f);
}